// Round 7
// baseline (2196.445 us; speedup 1.0000x reference)
//
#include <hip/hip_runtime.h>
#include <stdint.h>

#define N_EDGES 2000000
#define NUM_SEG 500000
#define HID 128
#define NBLK 4

typedef __attribute__((ext_vector_type(8))) unsigned short ushort8;
typedef __attribute__((ext_vector_type(8))) __bf16 bf16x8;
typedef __attribute__((ext_vector_type(4))) float float4v;
typedef __attribute__((ext_vector_type(2))) uint32_t uint2v;

__device__ inline unsigned short f32_to_bf16(float f) {
    return __builtin_bit_cast(unsigned short, (__bf16)f);   // native cvt, RNE
}

__device__ inline uint32_t pack_bf16(float lo, float hi) {
#if __has_builtin(__builtin_amdgcn_cvt_pk_bf16_f32)
    typedef __attribute__((ext_vector_type(2))) __bf16 bf16x2;
    bf16x2 r = __builtin_amdgcn_cvt_pk_bf16_f32(lo, hi);
    return __builtin_bit_cast(uint32_t, r);
#else
    return (uint32_t)f32_to_bf16(lo) | ((uint32_t)f32_to_bf16(hi) << 16);
#endif
}

// ---- prep: WbF[blk] = bf16(W_res*rms_w) in A-FRAGMENT ORDER:
//   i = blk*16384 + (kt*8+ft)*512 + lane*8 + j -> W'[m=ft*16+(lane&15)][k=kt*32+(lane>>4)*8+j]
// Also packs Win4[f] = {W_in[f][0..2], b_in[f]} and zero-fills segsum.
__global__ void prep_kernel(const float* __restrict__ W_res,
                            const float* __restrict__ rms_w,
                            const float* __restrict__ W_in,
                            const float* __restrict__ b_in,
                            unsigned short* __restrict__ WbF,
                            float* __restrict__ Win4,
                            float* __restrict__ segsum) {
    int i = blockIdx.x * 256 + threadIdx.x;
    if (i < 65536) {
        int blk = i >> 14;
        int r = i & 16383;
        int j = r & 7, lane = (r >> 3) & 63, ft = (r >> 9) & 7, kt = r >> 12;
        int cc = lane & 15, qq = lane >> 4;
        int row = ft * 16 + cc;
        int k = kt * 32 + qq * 8 + j;
        WbF[i] = f32_to_bf16(W_res[blk * 16384 + row * HID + k] * rms_w[blk * HID + k]);
    } else if (i < 65536 + 128) {
        int f = i - 65536;
        Win4[f * 4 + 0] = W_in[f * 3 + 0];
        Win4[f * 4 + 1] = W_in[f * 3 + 1];
        Win4[f * 4 + 2] = W_in[f * 3 + 2];
        Win4[f * 4 + 3] = b_in[f];
    } else {
        int s = i - 65536 - 128;
        if (s < NUM_SEG) segsum[s] = 0.0f;
    }
}

// ---- fused MLP.
// R7: SINGLE-VARIABLE change vs R6 — workgroup size 256 -> 1024 (16 waves), grid
// 15625 -> 3907, body unchanged (tail guards added). Rationale: R0-R6 proved time
// is invariant to LDS size, barriers, and W-path, but residency is pinned at
// 2 waves/SIMD by the waves-per-eu attribute on this toolchain (attr=3 collapses
// arch-VGPRs to 84 -> spill; no attr -> ~1 wave/EU). A 1024-thread wg forces all
// 16 waves onto one CU ATOMICALLY (barrier semantics) = 4 waves/SIMD by geometry
// -- the attribute cannot veto workgroup placement. The R6 barrier-free body has
// zero inter-wave coupling after the initial staging barrier, so a 16-wave wg
// costs nothing. LDS: hn 16x8KB + Win4 + xs = 139,264 B -> exactly 1 wg/CU.
// Tripwires: FETCH ~12.3-13 MB, WRITE ~7.8 MB, VGPR ~112 (balloon = spill, void).
__launch_bounds__(1024, 2)
__global__ void mlp_kernel(const float* __restrict__ x,           // [N,3]
                           const unsigned short* __restrict__ WbF,// [4,16384] bf16 A-frag order
                           const float* __restrict__ b_res,       // [4,128]
                           const float* __restrict__ W_out,       // [128]
                           const float* __restrict__ b_out,       // [1]
                           const float* __restrict__ Win4g,       // [128,4] = {w0,w1,w2,b_in}
                           float* __restrict__ e) {               // [N] = exp(logit)
    __shared__ __align__(16) unsigned short hnF[65536];   // 128 KB, B-frag order (8KB/wave x 16)
    __shared__ __align__(16) float4v Win4[128];           // 2 KB
    __shared__ float xs[1536];                            // 6 KB

    const int t = threadIdx.x;
    const int wave = t >> 6;   // 0..15
    const int lane = t & 63;
    const int q = lane >> 4;   // quad within wave
    const int c = lane & 15;   // lane within quad
    const long rowbase = (long)blockIdx.x * 512;

    // A-frag ping-pong buffers; preload blk0/kt0 (8 x global dwordx4, L1/L2-hot)
    ushort8 a0[8], a1[8];
    #pragma unroll
    for (int ft = 0; ft < 8; ++ft)
        a0[ft] = *(const ushort8*)&WbF[ft * 512 + lane * 8];

    for (int i = t; i < 1536; i += 1024) {
        long gi = rowbase * 3 + i;
        xs[i] = (gi < (long)N_EDGES * 3) ? x[gi] : 0.0f;
    }
    if (t < 128) Win4[t] = ((const float4v*)Win4g)[t];
    __syncthreads();   // the ONLY block-wide barrier in this kernel

    // ---- stage 1: h0[f][r] = W_in[f].x[r] + b_in[f], straight into D-layout regs
    float4v h[8][2];   // [ft][rt], component = reg
    {
        float xr[2][3];
        #pragma unroll
        for (int rt = 0; rt < 2; ++rt)
            #pragma unroll
            for (int k = 0; k < 3; ++k)
                xr[rt][k] = xs[(wave * 32 + rt * 16 + c) * 3 + k];
        #pragma unroll
        for (int ft = 0; ft < 8; ++ft)
            #pragma unroll
            for (int reg = 0; reg < 4; ++reg) {
                float4v wb = Win4[ft * 16 + q * 4 + reg];
                #pragma unroll
                for (int rt = 0; rt < 2; ++rt)
                    h[ft][rt][reg] = wb.w + xr[rt][0] * wb.x + xr[rt][1] * wb.y + xr[rt][2] * wb.z;
            }
    }

    // hnF bases (shorts), R0 full layout: slot (kt=ft>>1)*2+rt, 512 shorts/slot, wave-private.
    const int wbase = wave * 4096 + (q >> 1) * 128 + c * 8 + (q & 1) * 4;
    const int rbase = wave * 4096 + lane * 8;   // B-frag read base (lane-linear)
    const float4v zero4 = {0.0f, 0.0f, 0.0f, 0.0f};

    float4v acc[8][2];

    // one kt-step: optionally prefetch next kt's A-frags from global, then 2 B-reads + 16 MFMA
    auto ktstep = [&](ushort8 (&ac)[8], ushort8 (&an)[8], int kt,
                      const unsigned short* pn, bool first) {
        if (pn) {
            #pragma unroll
            for (int ft = 0; ft < 8; ++ft)
                an[ft] = *(const ushort8*)&pn[ft * 512 + lane * 8];
        }
        bf16x8 b0 = __builtin_bit_cast(bf16x8, *(const ushort8*)&hnF[rbase + (kt * 2 + 0) * 512]);
        bf16x8 b1 = __builtin_bit_cast(bf16x8, *(const ushort8*)&hnF[rbase + (kt * 2 + 1) * 512]);
        #pragma unroll
        for (int ft = 0; ft < 8; ++ft) {
            bf16x8 a = __builtin_bit_cast(bf16x8, ac[ft]);
            if (first) {
                acc[ft][0] = __builtin_amdgcn_mfma_f32_16x16x32_bf16(a, b0, zero4, 0, 0, 0);
                acc[ft][1] = __builtin_amdgcn_mfma_f32_16x16x32_bf16(a, b1, zero4, 0, 0, 0);
            } else {
                acc[ft][0] = __builtin_amdgcn_mfma_f32_16x16x32_bf16(a, b0, acc[ft][0], 0, 0, 0);
                acc[ft][1] = __builtin_amdgcn_mfma_f32_16x16x32_bf16(a, b1, acc[ft][1], 0, 0, 0);
            }
        }
    };

    // ---- residual blocks (NO barriers: hnF wave-private, W from global)
    for (int blk = 0; blk < NBLK; ++blk) {
        // write h as packed bf16 into B-frag-order LDS (16 x ds_write_b64).
        // Next blk's writes can't pass this blk's reads: same LDS object, in-order DS.
        #pragma unroll
        for (int ft = 0; ft < 8; ++ft) {
            const int foff = (ft >> 1) * 1024 + (ft & 1) * 256;
            #pragma unroll
            for (int rt = 0; rt < 2; ++rt) {
                uint2v v;
                v.x = pack_bf16(h[ft][rt][0], h[ft][rt][1]);
                v.y = pack_bf16(h[ft][rt][2], h[ft][rt][3]);
                *(uint2v*)&hnF[wbase + foff + rt * 512] = v;
            }
        }

        // rmsnorm scale per row (row = rt*16+c; in-lane over ft,reg then xor over q)
        float rs[2];
        #pragma unroll
        for (int rt = 0; rt < 2; ++rt) {
            float ss = 0.0f;
            #pragma unroll
            for (int ft = 0; ft < 8; ++ft) {
                #pragma unroll
                for (int reg = 0; reg < 4; ++reg) {
                    float vv = h[ft][rt][reg];
                    ss += vv * vv;
                }
            }
            ss += __shfl_xor(ss, 16, 64);
            ss += __shfl_xor(ss, 32, 64);
            rs[rt] = rsqrtf(ss * (1.0f / 128.0f) + 1.1920929e-7f);
        }

        // kt loop, fully static ping-pong: kt0 uses a0 (preloaded), kt3 prefetches
        // next blk's kt0 back into a0.
        const unsigned short* Wb = WbF + blk * 16384;
        ktstep(a0, a1, 0, Wb + 1 * 4096, true);
        ktstep(a1, a0, 1, Wb + 2 * 4096, false);
        ktstep(a0, a1, 2, Wb + 3 * 4096, false);
        ktstep(a1, a0, 3, blk < NBLK - 1 ? WbF + (blk + 1) * 16384 : nullptr, false);

        // epilogue: h += relu(rs[rt]*acc + b_res[f])
        const float4v* br4 = (const float4v*)(b_res + blk * HID);
        #pragma unroll
        for (int ft = 0; ft < 8; ++ft) {
            float4v bb = br4[ft * 4 + q];
            #pragma unroll
            for (int rt = 0; rt < 2; ++rt) {
                #pragma unroll
                for (int reg = 0; reg < 4; ++reg)
                    h[ft][rt][reg] += fmaxf(fmaf(rs[rt], acc[ft][rt][reg], bb[reg]), 0.0f);
            }
        }
    }

    // ---- output head: e[r] = exp(h[.][r] . W_out + b_out)
    const float bo = b_out[0];
    const float4v* wo4 = (const float4v*)W_out;
    float s[2] = {0.0f, 0.0f};
    #pragma unroll
    for (int ft = 0; ft < 8; ++ft) {
        float4v w = wo4[ft * 4 + q];
        #pragma unroll
        for (int rt = 0; rt < 2; ++rt) {
            #pragma unroll
            for (int reg = 0; reg < 4; ++reg)
                s[rt] += h[ft][rt][reg] * w[reg];
        }
    }
    #pragma unroll
    for (int rt = 0; rt < 2; ++rt) {
        s[rt] += __shfl_xor(s[rt], 16, 64);
        s[rt] += __shfl_xor(s[rt], 32, 64);
    }
    if (q == 0) {
        #pragma unroll
        for (int rt = 0; rt < 2; ++rt) {
            long row = rowbase + wave * 32 + rt * 16 + c;
            if (row < N_EDGES) e[row] = __expf(s[rt] + bo);
        }
    }
}

// ---- segment sum of e (sorted ids): wave-level segmented scan, tail lanes atomicAdd
__global__ void segsum_kernel(const float* __restrict__ e, const int* __restrict__ ids,
                              float* __restrict__ segsum) {
    int i = blockIdx.x * 256 + threadIdx.x;
    int lane = threadIdx.x & 63;
    float v = 0.0f; int id = -1;
    if (i < N_EDGES) { v = e[i]; id = ids[i]; }
    #pragma unroll
    for (int d = 1; d < 64; d <<= 1) {
        float ov = __shfl_up(v, d, 64);
        int oid = __shfl_up(id, d, 64);
        if (lane >= d && oid == id) v += ov;
    }
    int nid = __shfl_down(id, 1, 64);
    bool tail = (lane == 63) || (nid != id);
    if (id >= 0 && tail) atomicAdd(&segsum[id], v);
}

__global__ void norm_kernel(const float* __restrict__ e, const int* __restrict__ ids,
                            const float* __restrict__ segsum, float* __restrict__ out) {
    int i = blockIdx.x * 256 + threadIdx.x;
    if (i < N_EDGES) out[i] = e[i] / segsum[ids[i]];
}

extern "C" void kernel_launch(void* const* d_in, const int* in_sizes, int n_in,
                              void* d_out, int out_size, void* d_ws, size_t ws_size,
                              hipStream_t stream) {
    const float* x      = (const float*)d_in[0];
    const int*   ids    = (const int*)d_in[1];
    const float* W_in   = (const float*)d_in[2];
    const float* b_in   = (const float*)d_in[3];
    const float* rms_w  = (const float*)d_in[4];
    const float* W_res  = (const float*)d_in[5];
    const float* b_res  = (const float*)d_in[6];
    const float* W_out  = (const float*)d_in[7];
    const float* b_out  = (const float*)d_in[8];
    float* out = (float*)d_out;

    char* ws = (char*)d_ws;
    unsigned short* WbF = (unsigned short*)ws;                 // 131072 B
    float* Win4   = (float*)(ws + 131072);                     // 2048 B
    float* e      = (float*)(ws + 131072 + 2048);              // 8,000,000 B
    float* segsum = (float*)(ws + 131072 + 2048 + 8000000);    // 2,000,000 B

    int prep_items = 65536 + 128 + NUM_SEG;
    prep_kernel<<<(prep_items + 255) / 256, 256, 0, stream>>>(W_res, rms_w, W_in, b_in,
                                                              WbF, Win4, segsum);
    mlp_kernel<<<(N_EDGES + 511) / 512, 1024, 0, stream>>>(x, WbF, b_res, W_out, b_out, Win4, e);
    segsum_kernel<<<(N_EDGES + 255) / 256, 256, 0, stream>>>(e, ids, segsum);
    norm_kernel<<<(N_EDGES + 255) / 256, 256, 0, stream>>>(e, ids, segsum, out);
}

// Round 8
// 487.951 us; speedup vs baseline: 4.5014x; 4.5014x over previous
//
#include <hip/hip_runtime.h>
#include <stdint.h>

#define N_EDGES 2000000
#define NUM_SEG 500000
#define HID 128
#define NBLK 4

typedef __attribute__((ext_vector_type(8))) unsigned short ushort8;
typedef __attribute__((ext_vector_type(8))) __bf16 bf16x8;
typedef __attribute__((ext_vector_type(4))) float float4v;
typedef __attribute__((ext_vector_type(2))) uint32_t uint2v;

__device__ inline unsigned short f32_to_bf16(float f) {
    return __builtin_bit_cast(unsigned short, (__bf16)f);   // native cvt, RNE
}

__device__ inline uint32_t pack_bf16(float lo, float hi) {
#if __has_builtin(__builtin_amdgcn_cvt_pk_bf16_f32)
    typedef __attribute__((ext_vector_type(2))) __bf16 bf16x2;
    bf16x2 r = __builtin_amdgcn_cvt_pk_bf16_f32(lo, hi);
    return __builtin_bit_cast(uint32_t, r);
#else
    return (uint32_t)f32_to_bf16(lo) | ((uint32_t)f32_to_bf16(hi) << 16);
#endif
}

// ---- prep: WbF[blk] = bf16(W_res*rms_w) in A-FRAGMENT ORDER:
//   i = blk*16384 + (kt*8+ft)*512 + lane*8 + j -> W'[m=ft*16+(lane&15)][k=kt*32+(lane>>4)*8+j]
// Also packs Win4[f] = {W_in[f][0..2], b_in[f]} and zero-fills segsum.
__global__ void prep_kernel(const float* __restrict__ W_res,
                            const float* __restrict__ rms_w,
                            const float* __restrict__ W_in,
                            const float* __restrict__ b_in,
                            unsigned short* __restrict__ WbF,
                            float* __restrict__ Win4,
                            float* __restrict__ segsum) {
    int i = blockIdx.x * 256 + threadIdx.x;
    if (i < 65536) {
        int blk = i >> 14;
        int r = i & 16383;
        int j = r & 7, lane = (r >> 3) & 63, ft = (r >> 9) & 7, kt = r >> 12;
        int cc = lane & 15, qq = lane >> 4;
        int row = ft * 16 + cc;
        int k = kt * 32 + qq * 8 + j;
        WbF[i] = f32_to_bf16(W_res[blk * 16384 + row * HID + k] * rms_w[blk * HID + k]);
    } else if (i < 65536 + 128) {
        int f = i - 65536;
        Win4[f * 4 + 0] = W_in[f * 3 + 0];
        Win4[f * 4 + 1] = W_in[f * 3 + 1];
        Win4[f * 4 + 2] = W_in[f * 3 + 2];
        Win4[f * 4 + 3] = b_in[f];
    } else {
        int s = i - 65536 - 128;
        if (s < NUM_SEG) segsum[s] = 0.0f;
    }
}

// ---- fused MLP: 128 rows/wg, 4 waves x 32 rows.
// R8 (vs R6, which is the canonical barrier-free body): per-wave ILP deepening.
// R7 closed the occupancy chapter: per-wave state ~176 regs (112 arch + 64 acc)
// vs 512/EU register file => 2 waves/EU is the structural max (3x176=528>512);
// every attribute/geometry attempt to exceed it spilled. At 2 waves/EU the waves
// are ~90% stalled, so this round converts spare registers (~80 free at the
// 2-wave budget of 256/wave) into latency cover:
//   1. ALL 8 B-fragment ds_reads hoisted to right after the hn writes -- one
//      early lgkm drain (overlapped with rmsnorm) instead of 4 exposed ~120-cyc
//      waits inside the kt chain.
//   2. s_setprio(1) around each 16-MFMA cluster (barrier-free phase-diverse
//      waves = the regime where setprio measured +4-7%).
//   3. rmsnorm with 4 partial sums (dep chain 32 FMA -> 8).
// Tripwires: FETCH ~12.3 MB, WRITE ~7.8 MB, occupancy ~22.5% (change = spill/void).
__launch_bounds__(256, 2)
__global__ void mlp_kernel(const float* __restrict__ x,           // [N,3]
                           const unsigned short* __restrict__ WbF,// [4,16384] bf16 A-frag order
                           const float* __restrict__ b_res,       // [4,128]
                           const float* __restrict__ W_out,       // [128]
                           const float* __restrict__ b_out,       // [1]
                           const float* __restrict__ Win4g,       // [128,4] = {w0,w1,w2,b_in}
                           float* __restrict__ e) {               // [N] = exp(logit)
    __shared__ __align__(16) unsigned short hnF[16384];   // 32 KB, B-frag order (8KB/wave)
    __shared__ __align__(16) float4v Win4[128];
    __shared__ float xs[384];

    const int t = threadIdx.x;
    const int wave = t >> 6;
    const int lane = t & 63;
    const int q = lane >> 4;   // quad within wave
    const int c = lane & 15;   // lane within quad
    const long rowbase = (long)blockIdx.x * 128;

    // A-frag ping-pong buffers; preload blk0/kt0 (8 x global dwordx4, L2-hot)
    ushort8 a0[8], a1[8];
    #pragma unroll
    for (int ft = 0; ft < 8; ++ft)
        a0[ft] = *(const ushort8*)&WbF[ft * 512 + lane * 8];

    for (int i = t; i < 384; i += 256) xs[i] = x[rowbase * 3 + i];
    if (t < 128) Win4[t] = ((const float4v*)Win4g)[t];
    __syncthreads();   // the ONLY block-wide barrier in this kernel

    // ---- stage 1: h0[f][r] = W_in[f].x[r] + b_in[f], straight into D-layout regs
    float4v h[8][2];   // [ft][rt], component = reg
    {
        float xr[2][3];
        #pragma unroll
        for (int rt = 0; rt < 2; ++rt)
            #pragma unroll
            for (int k = 0; k < 3; ++k)
                xr[rt][k] = xs[(wave * 32 + rt * 16 + c) * 3 + k];
        #pragma unroll
        for (int ft = 0; ft < 8; ++ft)
            #pragma unroll
            for (int reg = 0; reg < 4; ++reg) {
                float4v wb = Win4[ft * 16 + q * 4 + reg];
                #pragma unroll
                for (int rt = 0; rt < 2; ++rt)
                    h[ft][rt][reg] = wb.w + xr[rt][0] * wb.x + xr[rt][1] * wb.y + xr[rt][2] * wb.z;
            }
    }

    // hnF bases (shorts), R0 full layout: slot (kt=ft>>1)*2+rt, 512 shorts/slot, wave-private.
    const int wbase = wave * 4096 + (q >> 1) * 128 + c * 8 + (q & 1) * 4;
    const int rbase = wave * 4096 + lane * 8;   // B-frag read base (lane-linear)
    const float4v zero4 = {0.0f, 0.0f, 0.0f, 0.0f};

    float4v acc[8][2];

    // one kt-step: prefetch next kt's A-frags from global, then 16 MFMA on preloaded B
    auto ktstep = [&](ushort8 (&ac)[8], ushort8 (&an)[8], bf16x8 b0, bf16x8 b1,
                      const unsigned short* pn, bool first) {
        if (pn) {
            #pragma unroll
            for (int ft = 0; ft < 8; ++ft)
                an[ft] = *(const ushort8*)&pn[ft * 512 + lane * 8];
        }
        __builtin_amdgcn_s_setprio(1);
        #pragma unroll
        for (int ft = 0; ft < 8; ++ft) {
            bf16x8 a = __builtin_bit_cast(bf16x8, ac[ft]);
            if (first) {
                acc[ft][0] = __builtin_amdgcn_mfma_f32_16x16x32_bf16(a, b0, zero4, 0, 0, 0);
                acc[ft][1] = __builtin_amdgcn_mfma_f32_16x16x32_bf16(a, b1, zero4, 0, 0, 0);
            } else {
                acc[ft][0] = __builtin_amdgcn_mfma_f32_16x16x32_bf16(a, b0, acc[ft][0], 0, 0, 0);
                acc[ft][1] = __builtin_amdgcn_mfma_f32_16x16x32_bf16(a, b1, acc[ft][1], 0, 0, 0);
            }
        }
        __builtin_amdgcn_s_setprio(0);
    };

    // ---- residual blocks (NO barriers: hnF wave-private, W from global)
    for (int blk = 0; blk < NBLK; ++blk) {
        // write h as packed bf16 into B-frag-order LDS (16 x ds_write_b64)
        #pragma unroll
        for (int ft = 0; ft < 8; ++ft) {
            const int foff = (ft >> 1) * 1024 + (ft & 1) * 256;
            #pragma unroll
            for (int rt = 0; rt < 2; ++rt) {
                uint2v v;
                v.x = pack_bf16(h[ft][rt][0], h[ft][rt][1]);
                v.y = pack_bf16(h[ft][rt][2], h[ft][rt][3]);
                *(uint2v*)&hnF[wbase + foff + rt * 512] = v;
            }
        }

        // hoist ALL 8 B-fragment reads (in-order DS pipe: reads issued after the
        // aliasing writes return new data; results land under the rmsnorm VALU)
        bf16x8 bfr[8];
        #pragma unroll
        for (int i = 0; i < 8; ++i)
            bfr[i] = __builtin_bit_cast(bf16x8, *(const ushort8*)&hnF[rbase + i * 512]);

        // rmsnorm scale per row: 4 partial sums (dep chain 8 FMA), then xor over q
        float rs[2];
        #pragma unroll
        for (int rt = 0; rt < 2; ++rt) {
            float p0 = 0.0f, p1 = 0.0f, p2 = 0.0f, p3 = 0.0f;
            #pragma unroll
            for (int ft = 0; ft < 8; ++ft) {
                p0 += h[ft][rt][0] * h[ft][rt][0];
                p1 += h[ft][rt][1] * h[ft][rt][1];
                p2 += h[ft][rt][2] * h[ft][rt][2];
                p3 += h[ft][rt][3] * h[ft][rt][3];
            }
            float ss = (p0 + p1) + (p2 + p3);
            ss += __shfl_xor(ss, 16, 64);
            ss += __shfl_xor(ss, 32, 64);
            rs[rt] = rsqrtf(ss * (1.0f / 128.0f) + 1.1920929e-7f);
        }

        // kt loop, static ping-pong: kt0 uses a0 (preloaded), kt3 prefetches
        // next blk's kt0 back into a0. B-frags come from the hoisted bfr[].
        const unsigned short* Wb = WbF + blk * 16384;
        ktstep(a0, a1, bfr[0], bfr[1], Wb + 1 * 4096, true);
        ktstep(a1, a0, bfr[2], bfr[3], Wb + 2 * 4096, false);
        ktstep(a0, a1, bfr[4], bfr[5], Wb + 3 * 4096, false);
        ktstep(a1, a0, bfr[6], bfr[7], blk < NBLK - 1 ? WbF + (blk + 1) * 16384 : nullptr, false);

        // epilogue: h += relu(rs[rt]*acc + b_res[f])
        const float4v* br4 = (const float4v*)(b_res + blk * HID);
        #pragma unroll
        for (int ft = 0; ft < 8; ++ft) {
            float4v bb = br4[ft * 4 + q];
            #pragma unroll
            for (int rt = 0; rt < 2; ++rt) {
                #pragma unroll
                for (int reg = 0; reg < 4; ++reg)
                    h[ft][rt][reg] += fmaxf(fmaf(rs[rt], acc[ft][rt][reg], bb[reg]), 0.0f);
            }
        }
    }

    // ---- output head: e[r] = exp(h[.][r] . W_out + b_out)
    const float bo = b_out[0];
    const float4v* wo4 = (const float4v*)W_out;
    float s[2] = {0.0f, 0.0f};
    #pragma unroll
    for (int ft = 0; ft < 8; ++ft) {
        float4v w = wo4[ft * 4 + q];
        #pragma unroll
        for (int rt = 0; rt < 2; ++rt) {
            #pragma unroll
            for (int reg = 0; reg < 4; ++reg)
                s[rt] += h[ft][rt][reg] * w[reg];
        }
    }
    #pragma unroll
    for (int rt = 0; rt < 2; ++rt) {
        s[rt] += __shfl_xor(s[rt], 16, 64);
        s[rt] += __shfl_xor(s[rt], 32, 64);
    }
    if (q == 0) {
        #pragma unroll
        for (int rt = 0; rt < 2; ++rt)
            e[rowbase + wave * 32 + rt * 16 + c] = __expf(s[rt] + bo);
    }
}

// ---- segment sum of e (sorted ids): wave-level segmented scan, tail lanes atomicAdd
__global__ void segsum_kernel(const float* __restrict__ e, const int* __restrict__ ids,
                              float* __restrict__ segsum) {
    int i = blockIdx.x * 256 + threadIdx.x;
    int lane = threadIdx.x & 63;
    float v = 0.0f; int id = -1;
    if (i < N_EDGES) { v = e[i]; id = ids[i]; }
    #pragma unroll
    for (int d = 1; d < 64; d <<= 1) {
        float ov = __shfl_up(v, d, 64);
        int oid = __shfl_up(id, d, 64);
        if (lane >= d && oid == id) v += ov;
    }
    int nid = __shfl_down(id, 1, 64);
    bool tail = (lane == 63) || (nid != id);
    if (id >= 0 && tail) atomicAdd(&segsum[id], v);
}

__global__ void norm_kernel(const float* __restrict__ e, const int* __restrict__ ids,
                            const float* __restrict__ segsum, float* __restrict__ out) {
    int i = blockIdx.x * 256 + threadIdx.x;
    if (i < N_EDGES) out[i] = e[i] / segsum[ids[i]];
}

extern "C" void kernel_launch(void* const* d_in, const int* in_sizes, int n_in,
                              void* d_out, int out_size, void* d_ws, size_t ws_size,
                              hipStream_t stream) {
    const float* x      = (const float*)d_in[0];
    const int*   ids    = (const int*)d_in[1];
    const float* W_in   = (const float*)d_in[2];
    const float* b_in   = (const float*)d_in[3];
    const float* rms_w  = (const float*)d_in[4];
    const float* W_res  = (const float*)d_in[5];
    const float* b_res  = (const float*)d_in[6];
    const float* W_out  = (const float*)d_in[7];
    const float* b_out  = (const float*)d_in[8];
    float* out = (float*)d_out;

    char* ws = (char*)d_ws;
    unsigned short* WbF = (unsigned short*)ws;                 // 131072 B
    float* Win4   = (float*)(ws + 131072);                     // 2048 B
    float* e      = (float*)(ws + 131072 + 2048);              // 8,000,000 B
    float* segsum = (float*)(ws + 131072 + 2048 + 8000000);    // 2,000,000 B

    int prep_items = 65536 + 128 + NUM_SEG;
    prep_kernel<<<(prep_items + 255) / 256, 256, 0, stream>>>(W_res, rms_w, W_in, b_in,
                                                              WbF, Win4, segsum);
    mlp_kernel<<<N_EDGES / 128, 256, 0, stream>>>(x, WbF, b_res, W_out, b_out, Win4, e);
    segsum_kernel<<<(N_EDGES + 255) / 256, 256, 0, stream>>>(e, ids, segsum);
    norm_kernel<<<(N_EDGES + 255) / 256, 256, 0, stream>>>(e, ids, segsum, out);
}